// Round 1
// baseline (1020.312 us; speedup 1.0000x reference)
//
#include <hip/hip_runtime.h>

// Problem constants
#define B 32
#define D 65536
#define H 512
#define M 16384
#define LOG_A (-6.907755278982137f)
#define LOG_B (4.605170185988092f)
#define VAR_Y 0.01f

typedef unsigned short ushort_t;
typedef unsigned int uint_t;

// ---- bf16 helpers ----
__device__ __forceinline__ float bflo(uint_t u){ u <<= 16; float f; __builtin_memcpy(&f,&u,4); return f; }
__device__ __forceinline__ float bfhi(uint_t u){ u &= 0xffff0000u; float f; __builtin_memcpy(&f,&u,4); return f; }
__device__ __forceinline__ float bf2f(ushort_t v){ uint_t u = ((uint_t)v)<<16; float f; __builtin_memcpy(&f,&u,4); return f; }
__device__ __forceinline__ ushort_t f2bf(float f){
  uint_t u; __builtin_memcpy(&u,&f,4);
  uint_t lsb = (u>>16)&1u; u += 0x7fffu + lsb;
  return (ushort_t)(u>>16);
}

// ---- dtype-generic loads (BF=true: bf16 ushorts; false: f32) — vectorized both ways ----
template<bool BF>
__device__ __forceinline__ float ldf(const void* p, size_t i){
  return BF ? bf2f(((const ushort_t*)p)[i]) : ((const float*)p)[i];
}
template<bool BF>
__device__ __forceinline__ void ld8(const void* p, size_t i, float* w){
  if(BF){
    uint4 v = *(const uint4*)((const ushort_t*)p + i);
    w[0]=bflo(v.x); w[1]=bfhi(v.x); w[2]=bflo(v.y); w[3]=bfhi(v.y);
    w[4]=bflo(v.z); w[5]=bfhi(v.z); w[6]=bflo(v.w); w[7]=bfhi(v.w);
  } else {
    float4 a = *(const float4*)((const float*)p + i);
    float4 b = *(const float4*)((const float*)p + i + 4);
    w[0]=a.x; w[1]=a.y; w[2]=a.z; w[3]=a.w; w[4]=b.x; w[5]=b.y; w[6]=b.z; w[7]=b.w;
  }
}
template<bool BF>
__device__ __forceinline__ void ld4(const void* p, size_t i, float* w){
  if(BF){
    uint2 v = *(const uint2*)((const ushort_t*)p + i);
    w[0]=bflo(v.x); w[1]=bfhi(v.x); w[2]=bflo(v.y); w[3]=bfhi(v.y);
  } else {
    float4 a = *(const float4*)((const float*)p + i);
    w[0]=a.x; w[1]=a.y; w[2]=a.z; w[3]=a.w;
  }
}

// Distribute-reduce: 64 accs/lane summed across 64 lanes; lane L ends with full sum of index L.
__device__ __forceinline__ void dist_reduce64(float* acc, int lane){
  #pragma unroll
  for(int s=0; s<6; ++s){
    int m = 32>>s;
    bool up = (lane & m) != 0;
    #pragma unroll
    for(int i=0;i<m;i++){
      float send  = up ? acc[i]   : acc[i+m];
      float other = __shfl_xor(send, m, 64);
      float keep  = up ? acc[i+m] : acc[i];
      acc[i] = keep + other;
    }
  }
}

// Distribute-reduce, 32 values across 64 lanes. Pre-combine lane L with L+32,
// then 5-stage butterfly. Lane L ends with full sum of index (L&31) in acc[0].
// Peak live state: 32 accs + temps (vs 64 for dist_reduce64) — keeps k7 spill-free.
__device__ __forceinline__ void dist_reduce32(float* acc, int lane){
  #pragma unroll
  for(int i=0;i<32;i++) acc[i] += __shfl_xor(acc[i], 32, 64);
  #pragma unroll
  for(int s=0; s<5; ++s){
    int m = 16>>s;
    bool up = (lane & m) != 0;
    #pragma unroll
    for(int i=0;i<m;i++){
      float send  = up ? acc[i]   : acc[i+m];
      float other = __shfl_xor(send, m, 64);
      float keep  = up ? acc[i+m] : acc[i];
      acc[i] = keep + other;
    }
  }
}

// Sniffer: W1 ~ N(0, 1/256). If bf16: every ushort's exponent field in [100,126] w.p. ~1.
// If f32: even-index ushorts are low mantissa bits -> exponent field ~uniform (P~0.105).
__global__ void k_sniff(const ushort_t* __restrict__ w1u, int* __restrict__ flag){
  int lane = threadIdx.x;
  ushort_t v = w1u[2*lane];
  int e = (v>>7) & 0xff;
  int ok = (e >= 100 && e <= 126) ? 1 : 0;
  unsigned long long m = __ballot(ok);
  if(lane==0) flag[0] = (__popcll(m) >= 48) ? 1 : 0;   // 1 = bf16, 0 = f32
}

// K0: per-batch sigma, var_x, t
template<bool BF>
__device__ __forceinline__ void k0_body(const void* t, float* sig){
  int b = threadIdx.x;
  if(b < B){
    float tf = ldf<BF>(t, b);
    float s  = expf(LOG_A + (LOG_B-LOG_A)*tf);
    float s2 = s*s;
    sig[b] = s; sig[B+b] = s2/(1.f+s2); sig[2*B+b] = tf;
  }
}
__global__ void k0_prep(const void* t, float* sig, const int* flag){
  if(flag[0]) k0_body<true>(t,sig); else k0_body<false>(t,sig);
}

// K1: split-K partials: P1[c][b][h] = sum_{d in chunk c (256 d's)} xt[b,d]*W1[d,h]
template<bool BF>
__device__ void k1_body(const void* xt, const void* W1, float* P1, float (*xs)[256]){
  int c = blockIdx.x; int d0 = c*256;
  for(int i = threadIdx.x; i < B*256; i += 256){
    int b = i>>8, dd = i&255;
    xs[b][dd] = ldf<BF>(xt, (size_t)b*D + d0 + dd);
  }
  __syncthreads();
  int lane = threadIdx.x & 63, wave = threadIdx.x >> 6;
  int h0 = lane*8, b0 = wave*8;
  float acc[8][8];
  #pragma unroll
  for(int i=0;i<8;i++)
    #pragma unroll
    for(int j=0;j<8;j++) acc[i][j]=0.f;
  for(int g=0; g<32; ++g){
    float w[8][8];
    #pragma unroll
    for(int k=0;k<8;k++) ld8<BF>(W1, (size_t)(d0+g*8+k)*H + h0, w[k]);
    #pragma unroll
    for(int k=0;k<8;k++){
      int dd = g*8+k;
      #pragma unroll
      for(int i=0;i<8;i++){
        float xv = xs[b0+i][dd];
        #pragma unroll
        for(int j=0;j<8;j++) acc[i][j] += xv*w[k][j];
      }
    }
  }
  float* po = P1 + (size_t)c*16384;
  #pragma unroll
  for(int i=0;i<8;i++){
    *(float4*)(po + (size_t)(b0+i)*H + h0)     = make_float4(acc[i][0],acc[i][1],acc[i][2],acc[i][3]);
    *(float4*)(po + (size_t)(b0+i)*H + h0 + 4) = make_float4(acc[i][4],acc[i][5],acc[i][6],acc[i][7]);
  }
}
__global__ __launch_bounds__(256) void k1_gemm1(const void* xt, const void* W1,
                                                float* P1, const int* flag){
  __shared__ float xs[B][256];
  if(flag[0]) k1_body<true>(xt,W1,P1,xs); else k1_body<false>(xt,W1,P1,xs);
}

// K2: reduce 256 partials, add b1 + t, tanh
template<bool BF>
__device__ __forceinline__ void k2_body(const float* P1, const void* b1, const float* sig, float* hbuf){
  int o = blockIdx.x*256 + threadIdx.x;
  float s = 0.f;
  #pragma unroll 8
  for(int c=0;c<256;c++) s += P1[(size_t)c*16384 + o];
  int b = o>>9, hh = o&511;
  float pre = s + ldf<BF>(b1, hh) + sig[2*B+b];
  hbuf[o] = tanhf(pre);
}
__global__ void k2_reduce1(const float* P1, const void* b1, const float* sig,
                           float* hbuf, const int* flag){
  if(flag[0]) k2_body<true>(P1,b1,sig,hbuf); else k2_body<false>(P1,b1,sig,hbuf);
}

// K3: z[b,d] = sum_h h[b,h]*W2[h,d] + b2[d]
template<bool BF>
__device__ void k3_body(const float* hbuf, const void* W2, const void* b2, float* z, float* hs){
  for(int i=threadIdx.x; i<B*H; i+=256) hs[i] = hbuf[i];
  __syncthreads();
  int lane = threadIdx.x & 63, wave = threadIdx.x >> 6;
  int d0 = blockIdx.x*256 + lane*4, b0 = wave*8;
  float acc[8][4];
  #pragma unroll
  for(int i=0;i<8;i++){ acc[i][0]=0.f; acc[i][1]=0.f; acc[i][2]=0.f; acc[i][3]=0.f; }
  for(int g=0; g<32; ++g){
    float w[16][4];
    #pragma unroll
    for(int k=0;k<16;k++) ld4<BF>(W2, (size_t)(g*16+k)*D + d0, w[k]);
    #pragma unroll
    for(int k=0;k<16;k++){
      int hh = g*16+k;
      #pragma unroll
      for(int i=0;i<8;i++){
        float hv = hs[(b0+i)*H + hh];
        acc[i][0]+=hv*w[k][0]; acc[i][1]+=hv*w[k][1]; acc[i][2]+=hv*w[k][2]; acc[i][3]+=hv*w[k][3];
      }
    }
  }
  float bb[4]; ld4<BF>(b2, d0, bb);
  #pragma unroll
  for(int i=0;i<8;i++){
    *(float4*)(z + (size_t)(b0+i)*D + d0) =
      make_float4(acc[i][0]+bb[0], acc[i][1]+bb[1], acc[i][2]+bb[2], acc[i][3]+bb[3]);
  }
}
__global__ __launch_bounds__(256) void k3_gemm2(const float* hbuf, const void* W2,
                                                const void* b2, float* z, const int* flag){
  __shared__ float hs[B*H];   // 64 KB
  if(flag[0]) k3_body<true>(hbuf,W2,b2,z,hs); else k3_body<false>(hbuf,W2,b2,z,hs);
}

// count multiplicities of obs_idx
__global__ void k_cnt(const int* __restrict__ idx, int* __restrict__ cnt){
  int m = blockIdx.x*256 + threadIdx.x;
  if(m < M) atomicAdd(&cnt[idx[m]], 1);
}

// K4: scatter residuals
template<bool BF>
__device__ __forceinline__ void k4s_body(const void* yo, const void* xt, const float* z,
                                         const int* idx, const float* sig, float* R){
  int id = blockIdx.x*256 + threadIdx.x;   // over B*M
  int b = id>>14, m = id&16383;
  int i = idx[m];
  size_t off = (size_t)b*D + i;
  float e0 = ldf<BF>(yo, id) - (ldf<BF>(xt, off) - sig[b]*z[off]);
  atomicAdd(&R[off], e0);
}
__global__ void k4_scatter(const void* yo, const void* xt, const float* z,
                           const int* idx, const float* sig, float* R, const int* flag){
  if(flag[0]) k4s_body<true>(yo,xt,z,idx,sig,R); else k4s_body<false>(yo,xt,z,idx,sig,R);
}

// closed-form CG + At fused, in place
__global__ void k4_solve(float* __restrict__ R, const int* __restrict__ cnt,
                         const float* __restrict__ sig){
  int id = blockIdx.x*256 + threadIdx.x;
  int b = id>>16, d = id&65535;
  R[id] = R[id] / (VAR_Y + sig[B+b]*(float)cnt[d]);
}

// K5: gh partials: P2[chunk][b][h'] = sum_{d in chunk} u[b,d]*W2[h',d]
template<bool BF>
__device__ void k5_body(const float* u, const void* W2, float* P2){
  int ht = blockIdx.x & 63, chunk = blockIdx.x >> 6;
  int lane = threadIdx.x & 63, wave = threadIdx.x >> 6;
  int h0 = ht*8, b0 = wave*8;
  float acc[64];
  #pragma unroll
  for(int k=0;k<64;k++) acc[k]=0.f;
  size_t dbase = (size_t)chunk*8192;
  for(int step=0; step<32; ++step){
    size_t d = dbase + step*256 + (size_t)lane*4;
    float wf[8][4];
    #pragma unroll
    for(int j=0;j<8;j++) ld4<BF>(W2, (size_t)(h0+j)*D + d, wf[j]);
    #pragma unroll
    for(int i=0;i<8;i++){
      float4 uv = *(const float4*)(u + (size_t)(b0+i)*D + d);
      #pragma unroll
      for(int j=0;j<8;j++)
        acc[i*8+j] += uv.x*wf[j][0] + uv.y*wf[j][1] + uv.z*wf[j][2] + uv.w*wf[j][3];
    }
  }
  dist_reduce64(acc, lane);
  int bsub = lane>>3, hsub = lane&7;
  P2[(size_t)chunk*16384 + (size_t)(b0+bsub)*H + (h0+hsub)] = acc[0];
}
__global__ __launch_bounds__(256) void k5_bwd1(const float* u, const void* W2,
                                               float* P2, const int* flag){
  if(flag[0]) k5_body<true>(u,W2,P2); else k5_body<false>(u,W2,P2);
}

// K6: gh = sum partials; gpre = gh * (1 - h^2)
__global__ void k6_gpre(const float* __restrict__ P2, const float* __restrict__ hbuf,
                        float* __restrict__ gpre){
  int o = blockIdx.x*256 + threadIdx.x;
  float s = 0.f;
  #pragma unroll
  for(int c=0;c<8;c++) s += P2[c*16384 + o];
  float hv = hbuf[o];
  gpre[o] = s*(1.f - hv*hv);
}

// K7: gxt[b,d] = sum_h gpre[b,h]*W1[d,h]; epilogue out = z - sigma*u + sigma^2*gxt
// REWORKED: old tile (8b x 8d per wave) held gp[8][8]+acc[64]+w[8] = 136+ live floats
// at 164 VGPRs -> register spills (~1.7 KB/thread => the 451 MB WRITE_SIZE,
// VALUBusy 12.5%, occupancy 11%, 231 us). New tile: 4b x 8d per wave
// (gp[4][8]=32 + acc[32] + w[8] ~= 72 live floats), 512-thread blocks so the
// 8 waves cover all 32 batches and W1 is still fetched exactly once per block.
template<bool BF>
__device__ void k7_body(const void* W1, const float* gpre, const float* z,
                        const float* u, const float* sig, void* out){
  int lane = threadIdx.x & 63, wave = threadIdx.x >> 6;  // wave 0..7
  int b0 = wave*4, h0 = lane*8;
  float gp[4][8];
  #pragma unroll
  for(int i=0;i<4;i++){
    float4 g0 = *(const float4*)(gpre + (b0+i)*H + h0);
    float4 g1 = *(const float4*)(gpre + (b0+i)*H + h0 + 4);
    gp[i][0]=g0.x; gp[i][1]=g0.y; gp[i][2]=g0.z; gp[i][3]=g0.w;
    gp[i][4]=g1.x; gp[i][5]=g1.y; gp[i][6]=g1.z; gp[i][7]=g1.w;
  }
  for(int dt=0; dt<8; ++dt){
    int d0 = blockIdx.x*64 + dt*8;
    float acc[32];
    #pragma unroll
    for(int ds2=0; ds2<8; ++ds2){
      float w[8]; ld8<BF>(W1, (size_t)(d0+ds2)*H + h0, w);
      #pragma unroll
      for(int i=0;i<4;i++){
        acc[i*8+ds2] = gp[i][0]*w[0]+gp[i][1]*w[1]+gp[i][2]*w[2]+gp[i][3]*w[3]
                     + gp[i][4]*w[4]+gp[i][5]*w[5]+gp[i][6]*w[6]+gp[i][7]*w[7];
      }
    }
    dist_reduce32(acc, lane);
    if(lane < 32){
      int b = b0 + (lane>>3), d = d0 + (lane&7);
      float s = sig[b];
      size_t off = (size_t)b*D + d;
      float o = z[off] - s*u[off] + s*s*acc[0];
      if(BF) ((ushort_t*)out)[off] = f2bf(o);
      else   ((float*)out)[off]    = o;
    }
  }
}
__global__ __launch_bounds__(512) void k7_final(const void* W1, const float* gpre,
                                                const float* z, const float* u,
                                                const float* sig, void* out, const int* flag){
  if(flag[0]) k7_body<true>(W1,gpre,z,u,sig,out); else k7_body<false>(W1,gpre,z,u,sig,out);
}

extern "C" void kernel_launch(void* const* d_in, const int* in_sizes, int n_in,
                              void* d_out, int out_size, void* d_ws, size_t ws_size,
                              hipStream_t stream){
  const void* xt = d_in[0];
  const void* t  = d_in[1];
  const void* W1 = d_in[2];
  const void* b1 = d_in[3];
  const void* W2 = d_in[4];
  const void* b2 = d_in[5];
  const void* yo = d_in[6];
  const int*  idx= (const int*)d_in[7];

  char* ws = (char*)d_ws;
  // ws layout — TOTAL 0x1100000 = 17.8 MB. P1 dead after k2; z/R alias it.
  float* sig  = (float*)(ws);              // 384 B
  float* hbuf = (float*)(ws + 0x10000);    // 64 KB
  float* gpre = (float*)(ws + 0x20000);    // 64 KB
  int*   cnt  = (int*)  (ws + 0x30000);    // 256 KB
  float* P2   = (float*)(ws + 0x70000);    // 512 KB (ends 0xF0000)
  int*   flag = (int*)  (ws + 0xF0000);    // 4 B
  float* P1   = (float*)(ws + 0x100000);   // 16 MB  (ends 0x1100000)
  float* z    = (float*)(ws + 0x100000);   // 8 MB, aliases P1 lower half (after k2)
  float* R    = (float*)(ws + 0x900000);   // 8 MB, aliases P1 upper half (after k2)

  hipMemsetAsync(cnt, 0, (size_t)D*sizeof(int), stream);

  hipLaunchKernelGGL(k_sniff,   dim3(1),    dim3(64),  0, stream, (const ushort_t*)W1, flag);
  hipLaunchKernelGGL(k0_prep,   dim3(1),    dim3(64),  0, stream, t, sig, flag);
  hipLaunchKernelGGL(k1_gemm1,  dim3(256),  dim3(256), 0, stream, xt, W1, P1, flag);
  hipLaunchKernelGGL(k2_reduce1,dim3(64),   dim3(256), 0, stream, P1, b1, sig, hbuf, flag);
  // P1 now dead; zero R (aliases P1 upper half) before scatter.
  hipMemsetAsync(R, 0, (size_t)B*D*sizeof(float), stream);
  hipLaunchKernelGGL(k3_gemm2,  dim3(256),  dim3(256), 0, stream, hbuf, W2, b2, z, flag);
  hipLaunchKernelGGL(k_cnt,     dim3(64),   dim3(256), 0, stream, idx, cnt);
  hipLaunchKernelGGL(k4_scatter,dim3(2048), dim3(256), 0, stream, yo, xt, z, idx, sig, R, flag);
  hipLaunchKernelGGL(k4_solve,  dim3(8192), dim3(256), 0, stream, R, cnt, sig);
  hipLaunchKernelGGL(k5_bwd1,   dim3(512),  dim3(256), 0, stream, R, W2, P2, flag);
  hipLaunchKernelGGL(k6_gpre,   dim3(64),   dim3(256), 0, stream, P2, hbuf, gpre);
  hipLaunchKernelGGL(k7_final,  dim3(1024), dim3(512), 0, stream, W1, gpre, z, R, sig, d_out, flag);
}

// Round 2
// 759.030 us; speedup vs baseline: 1.3442x; 1.3442x over previous
//
#include <hip/hip_runtime.h>

// Problem constants
#define B 32
#define D 65536
#define H 512
#define M 16384
#define LOG_A (-6.907755278982137f)
#define LOG_B (4.605170185988092f)
#define VAR_Y 0.01f

typedef unsigned short ushort_t;
typedef unsigned int uint_t;

// ---- bf16 helpers ----
__device__ __forceinline__ float bflo(uint_t u){ u <<= 16; float f; __builtin_memcpy(&f,&u,4); return f; }
__device__ __forceinline__ float bfhi(uint_t u){ u &= 0xffff0000u; float f; __builtin_memcpy(&f,&u,4); return f; }
__device__ __forceinline__ float bf2f(ushort_t v){ uint_t u = ((uint_t)v)<<16; float f; __builtin_memcpy(&f,&u,4); return f; }
__device__ __forceinline__ ushort_t f2bf(float f){
  uint_t u; __builtin_memcpy(&u,&f,4);
  uint_t lsb = (u>>16)&1u; u += 0x7fffu + lsb;
  return (ushort_t)(u>>16);
}

// ---- dtype-generic loads (BF=true: bf16 ushorts; false: f32) — vectorized both ways ----
template<bool BF>
__device__ __forceinline__ float ldf(const void* p, size_t i){
  return BF ? bf2f(((const ushort_t*)p)[i]) : ((const float*)p)[i];
}
template<bool BF>
__device__ __forceinline__ void ld8(const void* p, size_t i, float* w){
  if(BF){
    uint4 v = *(const uint4*)((const ushort_t*)p + i);
    w[0]=bflo(v.x); w[1]=bfhi(v.x); w[2]=bflo(v.y); w[3]=bfhi(v.y);
    w[4]=bflo(v.z); w[5]=bfhi(v.z); w[6]=bflo(v.w); w[7]=bfhi(v.w);
  } else {
    float4 a = *(const float4*)((const float*)p + i);
    float4 b = *(const float4*)((const float*)p + i + 4);
    w[0]=a.x; w[1]=a.y; w[2]=a.z; w[3]=a.w; w[4]=b.x; w[5]=b.y; w[6]=b.z; w[7]=b.w;
  }
}
template<bool BF>
__device__ __forceinline__ void ld4(const void* p, size_t i, float* w){
  if(BF){
    uint2 v = *(const uint2*)((const ushort_t*)p + i);
    w[0]=bflo(v.x); w[1]=bfhi(v.x); w[2]=bflo(v.y); w[3]=bfhi(v.y);
  } else {
    float4 a = *(const float4*)((const float*)p + i);
    w[0]=a.x; w[1]=a.y; w[2]=a.z; w[3]=a.w;
  }
}

// Distribute-reduce: 64 accs/lane summed across 64 lanes; lane L ends with full sum of index L.
// Cost ~4 ops per reduced output — amortization over 64 outputs is why the 8b×8d tile wins.
__device__ __forceinline__ void dist_reduce64(float* acc, int lane){
  #pragma unroll
  for(int s=0; s<6; ++s){
    int m = 32>>s;
    bool up = (lane & m) != 0;
    #pragma unroll
    for(int i=0;i<m;i++){
      float send  = up ? acc[i]   : acc[i+m];
      float other = __shfl_xor(send, m, 64);
      float keep  = up ? acc[i+m] : acc[i];
      acc[i] = keep + other;
    }
  }
}

// Sniffer: W1 ~ N(0, 1/256). If bf16: every ushort's exponent field in [100,126] w.p. ~1.
// If f32: even-index ushorts are low mantissa bits -> exponent field ~uniform (P~0.105).
__global__ void k_sniff(const ushort_t* __restrict__ w1u, int* __restrict__ flag){
  int lane = threadIdx.x;
  ushort_t v = w1u[2*lane];
  int e = (v>>7) & 0xff;
  int ok = (e >= 100 && e <= 126) ? 1 : 0;
  unsigned long long m = __ballot(ok);
  if(lane==0) flag[0] = (__popcll(m) >= 48) ? 1 : 0;   // 1 = bf16, 0 = f32
}

// K0: per-batch sigma, var_x, t
template<bool BF>
__device__ __forceinline__ void k0_body(const void* t, float* sig){
  int b = threadIdx.x;
  if(b < B){
    float tf = ldf<BF>(t, b);
    float s  = expf(LOG_A + (LOG_B-LOG_A)*tf);
    float s2 = s*s;
    sig[b] = s; sig[B+b] = s2/(1.f+s2); sig[2*B+b] = tf;
  }
}
__global__ void k0_prep(const void* t, float* sig, const int* flag){
  if(flag[0]) k0_body<true>(t,sig); else k0_body<false>(t,sig);
}

// K1: split-K partials: P1[c][b][h] = sum_{d in chunk c (256 d's)} xt[b,d]*W1[d,h]
template<bool BF>
__device__ void k1_body(const void* xt, const void* W1, float* P1, float (*xs)[256]){
  int c = blockIdx.x; int d0 = c*256;
  for(int i = threadIdx.x; i < B*256; i += 256){
    int b = i>>8, dd = i&255;
    xs[b][dd] = ldf<BF>(xt, (size_t)b*D + d0 + dd);
  }
  __syncthreads();
  int lane = threadIdx.x & 63, wave = threadIdx.x >> 6;
  int h0 = lane*8, b0 = wave*8;
  float acc[8][8];
  #pragma unroll
  for(int i=0;i<8;i++)
    #pragma unroll
    for(int j=0;j<8;j++) acc[i][j]=0.f;
  for(int g=0; g<32; ++g){
    float w[8][8];
    #pragma unroll
    for(int k=0;k<8;k++) ld8<BF>(W1, (size_t)(d0+g*8+k)*H + h0, w[k]);
    #pragma unroll
    for(int k=0;k<8;k++){
      int dd = g*8+k;
      #pragma unroll
      for(int i=0;i<8;i++){
        float xv = xs[b0+i][dd];
        #pragma unroll
        for(int j=0;j<8;j++) acc[i][j] += xv*w[k][j];
      }
    }
  }
  float* po = P1 + (size_t)c*16384;
  #pragma unroll
  for(int i=0;i<8;i++){
    *(float4*)(po + (size_t)(b0+i)*H + h0)     = make_float4(acc[i][0],acc[i][1],acc[i][2],acc[i][3]);
    *(float4*)(po + (size_t)(b0+i)*H + h0 + 4) = make_float4(acc[i][4],acc[i][5],acc[i][6],acc[i][7]);
  }
}
__global__ __launch_bounds__(256) void k1_gemm1(const void* xt, const void* W1,
                                                float* P1, const int* flag){
  __shared__ float xs[B][256];
  if(flag[0]) k1_body<true>(xt,W1,P1,xs); else k1_body<false>(xt,W1,P1,xs);
}

// K2: reduce 256 partials, add b1 + t, tanh
template<bool BF>
__device__ __forceinline__ void k2_body(const float* P1, const void* b1, const float* sig, float* hbuf){
  int o = blockIdx.x*256 + threadIdx.x;
  float s = 0.f;
  #pragma unroll 8
  for(int c=0;c<256;c++) s += P1[(size_t)c*16384 + o];
  int b = o>>9, hh = o&511;
  float pre = s + ldf<BF>(b1, hh) + sig[2*B+b];
  hbuf[o] = tanhf(pre);
}
__global__ void k2_reduce1(const float* P1, const void* b1, const float* sig,
                           float* hbuf, const int* flag){
  if(flag[0]) k2_body<true>(P1,b1,sig,hbuf); else k2_body<false>(P1,b1,sig,hbuf);
}

// K3: z[b,d] = sum_h h[b,h]*W2[h,d] + b2[d]
template<bool BF>
__device__ void k3_body(const float* hbuf, const void* W2, const void* b2, float* z, float* hs){
  for(int i=threadIdx.x; i<B*H; i+=256) hs[i] = hbuf[i];
  __syncthreads();
  int lane = threadIdx.x & 63, wave = threadIdx.x >> 6;
  int d0 = blockIdx.x*256 + lane*4, b0 = wave*8;
  float acc[8][4];
  #pragma unroll
  for(int i=0;i<8;i++){ acc[i][0]=0.f; acc[i][1]=0.f; acc[i][2]=0.f; acc[i][3]=0.f; }
  for(int g=0; g<32; ++g){
    float w[16][4];
    #pragma unroll
    for(int k=0;k<16;k++) ld4<BF>(W2, (size_t)(g*16+k)*D + d0, w[k]);
    #pragma unroll
    for(int k=0;k<16;k++){
      int hh = g*16+k;
      #pragma unroll
      for(int i=0;i<8;i++){
        float hv = hs[(b0+i)*H + hh];
        acc[i][0]+=hv*w[k][0]; acc[i][1]+=hv*w[k][1]; acc[i][2]+=hv*w[k][2]; acc[i][3]+=hv*w[k][3];
      }
    }
  }
  float bb[4]; ld4<BF>(b2, d0, bb);
  #pragma unroll
  for(int i=0;i<8;i++){
    *(float4*)(z + (size_t)(b0+i)*D + d0) =
      make_float4(acc[i][0]+bb[0], acc[i][1]+bb[1], acc[i][2]+bb[2], acc[i][3]+bb[3]);
  }
}
__global__ __launch_bounds__(256) void k3_gemm2(const float* hbuf, const void* W2,
                                                const void* b2, float* z, const int* flag){
  __shared__ float hs[B*H];   // 64 KB
  if(flag[0]) k3_body<true>(hbuf,W2,b2,z,hs); else k3_body<false>(hbuf,W2,b2,z,hs);
}

// count multiplicities of obs_idx
__global__ void k_cnt(const int* __restrict__ idx, int* __restrict__ cnt){
  int m = blockIdx.x*256 + threadIdx.x;
  if(m < M) atomicAdd(&cnt[idx[m]], 1);
}

// K4: scatter residuals
template<bool BF>
__device__ __forceinline__ void k4s_body(const void* yo, const void* xt, const float* z,
                                         const int* idx, const float* sig, float* R){
  int id = blockIdx.x*256 + threadIdx.x;   // over B*M
  int b = id>>14, m = id&16383;
  int i = idx[m];
  size_t off = (size_t)b*D + i;
  float e0 = ldf<BF>(yo, id) - (ldf<BF>(xt, off) - sig[b]*z[off]);
  atomicAdd(&R[off], e0);
}
__global__ void k4_scatter(const void* yo, const void* xt, const float* z,
                           const int* idx, const float* sig, float* R, const int* flag){
  if(flag[0]) k4s_body<true>(yo,xt,z,idx,sig,R); else k4s_body<false>(yo,xt,z,idx,sig,R);
}

// closed-form CG + At fused, in place
__global__ void k4_solve(float* __restrict__ R, const int* __restrict__ cnt,
                         const float* __restrict__ sig){
  int id = blockIdx.x*256 + threadIdx.x;
  int b = id>>16, d = id&65535;
  R[id] = R[id] / (VAR_Y + sig[B+b]*(float)cnt[d]);
}

// K5: gh partials: P2[chunk][b][h'] = sum_{d in chunk} u[b,d]*W2[h',d]
template<bool BF>
__device__ void k5_body(const float* u, const void* W2, float* P2){
  int ht = blockIdx.x & 63, chunk = blockIdx.x >> 6;
  int lane = threadIdx.x & 63, wave = threadIdx.x >> 6;
  int h0 = ht*8, b0 = wave*8;
  float acc[64];
  #pragma unroll
  for(int k=0;k<64;k++) acc[k]=0.f;
  size_t dbase = (size_t)chunk*8192;
  for(int step=0; step<32; ++step){
    size_t d = dbase + step*256 + (size_t)lane*4;
    float wf[8][4];
    #pragma unroll
    for(int j=0;j<8;j++) ld4<BF>(W2, (size_t)(h0+j)*D + d, wf[j]);
    #pragma unroll
    for(int i=0;i<8;i++){
      float4 uv = *(const float4*)(u + (size_t)(b0+i)*D + d);
      #pragma unroll
      for(int j=0;j<8;j++)
        acc[i*8+j] += uv.x*wf[j][0] + uv.y*wf[j][1] + uv.z*wf[j][2] + uv.w*wf[j][3];
    }
  }
  dist_reduce64(acc, lane);
  int bsub = lane>>3, hsub = lane&7;
  P2[(size_t)chunk*16384 + (size_t)(b0+bsub)*H + (h0+hsub)] = acc[0];
}
__global__ __launch_bounds__(256) void k5_bwd1(const float* u, const void* W2,
                                               float* P2, const int* flag){
  if(flag[0]) k5_body<true>(u,W2,P2); else k5_body<false>(u,W2,P2);
}

// K6: gh = sum partials; gpre = gh * (1 - h^2)
__global__ void k6_gpre(const float* __restrict__ P2, const float* __restrict__ hbuf,
                        float* __restrict__ gpre){
  int o = blockIdx.x*256 + threadIdx.x;
  float s = 0.f;
  #pragma unroll
  for(int c=0;c<8;c++) s += P2[c*16384 + o];
  float hv = hbuf[o];
  gpre[o] = s*(1.f - hv*hv);
}

// K7: gxt[b,d] = sum_h gpre[b,h]*W1[d,h]; epilogue out = z - sigma*u + sigma^2*gxt
// HISTORY: 8b×8d tile + dist_reduce64 (R0) = right structure (reduce amortized to
// ~4 ops per output), but at the default VGPR target (164) it spilled ~1.7KB/thread
// -> 451 MB scratch writes -> 231 us. The 4b×8d + dist_reduce32 attempt (R1) removed
// spills but doubled reduce cost per output + serialized butterfly tails -> 524 us.
// FIX: keep 8b×8d, allow full register budget via __launch_bounds__(256, 1).
// Peak live ~180 VGPR < 256; occupancy 2 waves/SIMD is plenty (streaming loads,
// W1 read exactly once globally = 10 us HBM floor).
template<bool BF>
__device__ void k7_body(const void* W1, const float* gpre, const float* z,
                        const float* u, const float* sig, void* out){
  int lane = threadIdx.x & 63, wave = threadIdx.x >> 6;
  int b0 = wave*8, h0 = lane*8;
  float gp[8][8];
  #pragma unroll
  for(int i=0;i<8;i++){
    float4 g0 = *(const float4*)(gpre + (b0+i)*H + h0);
    float4 g1 = *(const float4*)(gpre + (b0+i)*H + h0 + 4);
    gp[i][0]=g0.x; gp[i][1]=g0.y; gp[i][2]=g0.z; gp[i][3]=g0.w;
    gp[i][4]=g1.x; gp[i][5]=g1.y; gp[i][6]=g1.z; gp[i][7]=g1.w;
  }
  for(int dt=0; dt<8; ++dt){
    int d0 = blockIdx.x*64 + dt*8;
    float acc[64];
    #pragma unroll
    for(int k=0;k<64;k++) acc[k]=0.f;
    #pragma unroll
    for(int ds2=0; ds2<8; ++ds2){
      float w[8]; ld8<BF>(W1, (size_t)(d0+ds2)*H + h0, w);
      #pragma unroll
      for(int i=0;i<8;i++){
        float s2 = gp[i][0]*w[0]+gp[i][1]*w[1]+gp[i][2]*w[2]+gp[i][3]*w[3]
                 + gp[i][4]*w[4]+gp[i][5]*w[5]+gp[i][6]*w[6]+gp[i][7]*w[7];
        acc[i*8+ds2] += s2;
      }
    }
    dist_reduce64(acc, lane);
    int bsub = lane>>3, dsub = lane&7;
    int b = b0 + bsub, d = d0 + dsub;
    float s = sig[b];
    size_t off = (size_t)b*D + d;
    float o = z[off] - s*u[off] + s*s*acc[0];
    if(BF) ((ushort_t*)out)[off] = f2bf(o);
    else   ((float*)out)[off]    = o;
  }
}
__global__ __launch_bounds__(256, 1) void k7_final(const void* W1, const float* gpre,
                                                   const float* z, const float* u,
                                                   const float* sig, void* out, const int* flag){
  if(flag[0]) k7_body<true>(W1,gpre,z,u,sig,out); else k7_body<false>(W1,gpre,z,u,sig,out);
}

extern "C" void kernel_launch(void* const* d_in, const int* in_sizes, int n_in,
                              void* d_out, int out_size, void* d_ws, size_t ws_size,
                              hipStream_t stream){
  const void* xt = d_in[0];
  const void* t  = d_in[1];
  const void* W1 = d_in[2];
  const void* b1 = d_in[3];
  const void* W2 = d_in[4];
  const void* b2 = d_in[5];
  const void* yo = d_in[6];
  const int*  idx= (const int*)d_in[7];

  char* ws = (char*)d_ws;
  // ws layout — TOTAL 0x1100000 = 17.8 MB. P1 dead after k2; z/R alias it.
  float* sig  = (float*)(ws);              // 384 B
  float* hbuf = (float*)(ws + 0x10000);    // 64 KB
  float* gpre = (float*)(ws + 0x20000);    // 64 KB
  int*   cnt  = (int*)  (ws + 0x30000);    // 256 KB
  float* P2   = (float*)(ws + 0x70000);    // 512 KB (ends 0xF0000)
  int*   flag = (int*)  (ws + 0xF0000);    // 4 B
  float* P1   = (float*)(ws + 0x100000);   // 16 MB  (ends 0x1100000)
  float* z    = (float*)(ws + 0x100000);   // 8 MB, aliases P1 lower half (after k2)
  float* R    = (float*)(ws + 0x900000);   // 8 MB, aliases P1 upper half (after k2)

  hipMemsetAsync(cnt, 0, (size_t)D*sizeof(int), stream);

  hipLaunchKernelGGL(k_sniff,   dim3(1),    dim3(64),  0, stream, (const ushort_t*)W1, flag);
  hipLaunchKernelGGL(k0_prep,   dim3(1),    dim3(64),  0, stream, t, sig, flag);
  hipLaunchKernelGGL(k1_gemm1,  dim3(256),  dim3(256), 0, stream, xt, W1, P1, flag);
  hipLaunchKernelGGL(k2_reduce1,dim3(64),   dim3(256), 0, stream, P1, b1, sig, hbuf, flag);
  // P1 now dead; zero R (aliases P1 upper half) before scatter.
  hipMemsetAsync(R, 0, (size_t)B*D*sizeof(float), stream);
  hipLaunchKernelGGL(k3_gemm2,  dim3(256),  dim3(256), 0, stream, hbuf, W2, b2, z, flag);
  hipLaunchKernelGGL(k_cnt,     dim3(64),   dim3(256), 0, stream, idx, cnt);
  hipLaunchKernelGGL(k4_scatter,dim3(2048), dim3(256), 0, stream, yo, xt, z, idx, sig, R, flag);
  hipLaunchKernelGGL(k4_solve,  dim3(8192), dim3(256), 0, stream, R, cnt, sig);
  hipLaunchKernelGGL(k5_bwd1,   dim3(512),  dim3(256), 0, stream, R, W2, P2, flag);
  hipLaunchKernelGGL(k6_gpre,   dim3(64),   dim3(256), 0, stream, P2, hbuf, gpre);
  hipLaunchKernelGGL(k7_final,  dim3(1024), dim3(256), 0, stream, W1, gpre, z, R, sig, d_out, flag);
}